// Round 1
// baseline (678.616 us; speedup 1.0000x reference)
//
#include <hip/hip_runtime.h>
#include <hip/hip_bf16.h>

// Problem constants (static per reference)
#define EMBED   256
#define HEADS   8
#define LEVELS  3
#define POINTS  4
#define BATCH   2
#define QLEN    21504
#define SLEN    21504
#define HEADDIM 32

// ---------------- GEMM: C[M,N] = A[M,K=256] @ W[N,K]^T + bias[N] ----------------
#define GEMM_BM 64
#define GEMM_BN 64
#define GEMM_BK 16
#define GEMM_K  256

__global__ __launch_bounds__(256)
void gemm_bias_kernel(const float* __restrict__ A, const float* __restrict__ W,
                      const float* __restrict__ bias, float* __restrict__ C,
                      int M, int N)
{
    __shared__ float As[GEMM_BK][GEMM_BM];
    __shared__ float Ws[GEMM_BK][GEMM_BN];
    const int tid = threadIdx.x;
    const int bm  = blockIdx.y * GEMM_BM;
    const int bn  = blockIdx.x * GEMM_BN;
    const int tm  = (tid >> 4) << 2;   // 0..60 step 4 (row in tile)
    const int tn  = (tid & 15) << 2;   // 0..60 step 4 (col in tile)
    const int lrow = tid >> 2;         // 0..63  (loader row)
    const int lk   = (tid & 3) << 2;   // 0,4,8,12 (loader k base)

    float acc[4][4];
    #pragma unroll
    for (int i = 0; i < 4; ++i)
        #pragma unroll
        for (int j = 0; j < 4; ++j) acc[i][j] = 0.f;

    const float* Aptr = A + (size_t)(bm + lrow) * GEMM_K + lk;
    const bool wvalid = (bn + lrow) < N;
    const float* Wptr = W + (size_t)(wvalid ? (bn + lrow) : 0) * GEMM_K + lk;

    for (int k0 = 0; k0 < GEMM_K; k0 += GEMM_BK) {
        float4 av = *(const float4*)(Aptr + k0);
        float4 wv = make_float4(0.f, 0.f, 0.f, 0.f);
        if (wvalid) wv = *(const float4*)(Wptr + k0);
        __syncthreads();
        As[lk + 0][lrow] = av.x; As[lk + 1][lrow] = av.y;
        As[lk + 2][lrow] = av.z; As[lk + 3][lrow] = av.w;
        Ws[lk + 0][lrow] = wv.x; Ws[lk + 1][lrow] = wv.y;
        Ws[lk + 2][lrow] = wv.z; Ws[lk + 3][lrow] = wv.w;
        __syncthreads();
        #pragma unroll
        for (int kk = 0; kk < GEMM_BK; ++kk) {
            float4 a = *(const float4*)&As[kk][tm];
            float4 b = *(const float4*)&Ws[kk][tn];
            acc[0][0] = fmaf(a.x, b.x, acc[0][0]);
            acc[0][1] = fmaf(a.x, b.y, acc[0][1]);
            acc[0][2] = fmaf(a.x, b.z, acc[0][2]);
            acc[0][3] = fmaf(a.x, b.w, acc[0][3]);
            acc[1][0] = fmaf(a.y, b.x, acc[1][0]);
            acc[1][1] = fmaf(a.y, b.y, acc[1][1]);
            acc[1][2] = fmaf(a.y, b.z, acc[1][2]);
            acc[1][3] = fmaf(a.y, b.w, acc[1][3]);
            acc[2][0] = fmaf(a.z, b.x, acc[2][0]);
            acc[2][1] = fmaf(a.z, b.y, acc[2][1]);
            acc[2][2] = fmaf(a.z, b.z, acc[2][2]);
            acc[2][3] = fmaf(a.z, b.w, acc[2][3]);
            acc[3][0] = fmaf(a.w, b.x, acc[3][0]);
            acc[3][1] = fmaf(a.w, b.y, acc[3][1]);
            acc[3][2] = fmaf(a.w, b.z, acc[3][2]);
            acc[3][3] = fmaf(a.w, b.w, acc[3][3]);
        }
    }

    const int col = bn + tn;
    if (col < N) {  // N % 4 == 0 and col % 4 == 0, so col < N implies col+3 < N
        float4 bv = *(const float4*)(bias + col);
        #pragma unroll
        for (int i = 0; i < 4; ++i) {
            const int row = bm + tm + i;
            float4 o;
            o.x = acc[i][0] + bv.x;
            o.y = acc[i][1] + bv.y;
            o.z = acc[i][2] + bv.z;
            o.w = acc[i][3] + bv.w;
            *(float4*)(C + (size_t)row * N + col) = o;
        }
    }
}

// ---------------- Sampling: softmax + bilinear gather + weighted sum ----------------
// One 32-lane group per (b,q,h); lane = channel d. 8 groups / 256-thread block.
__global__ __launch_bounds__(256)
void msda_sample_kernel(const float* __restrict__ value,  // [B, S, 256]
                        const float* __restrict__ off,    // [B*Q, 192] (h,l,p,2)
                        const float* __restrict__ aw,     // [B*Q, 96]  (h,l,p)
                        const float* __restrict__ ref,    // [B, Q, L, 2]
                        float* __restrict__ attn)         // [B*Q, 256]
{
    const int g    = blockIdx.x * 8 + (threadIdx.x >> 5);
    const int lane = threadIdx.x & 31;
    const int h    = g & 7;
    const int bq   = g >> 3;           // b*QLEN + q
    const int b    = bq / QLEN;

    // softmax over the 12 (level, point) weights of this head
    const float* awp = aw + (size_t)bq * 96 + h * 12;
    float e[12];
    float mx = awp[0];
    #pragma unroll
    for (int i = 1; i < 12; ++i) mx = fmaxf(mx, awp[i]);
    float s = 0.f;
    #pragma unroll
    for (int i = 0; i < 12; ++i) { e[i] = __expf(awp[i] - mx); s += e[i]; }
    const float inv = 1.f / s;

    const float* offp = off + (size_t)bq * 192 + h * 24;
    const float* refp = ref + (size_t)bq * 6;
    const float* vb   = value + (size_t)b * SLEN * EMBED + h * HEADDIM + lane;

    const int Wl[3] = {128, 64, 32};
    const int Hl[3] = {128, 64, 32};
    const int st[3] = {0, 16384, 20480};

    float acc = 0.f;
    #pragma unroll
    for (int l = 0; l < 3; ++l) {
        const float rx = refp[2 * l + 0];
        const float ry = refp[2 * l + 1];
        const float fw = (float)Wl[l];
        const float fh = (float)Hl[l];
        const float* base = vb + (size_t)st[l] * EMBED;
        #pragma unroll
        for (int p = 0; p < 4; ++p) {
            const float ox = offp[l * 8 + p * 2 + 0];
            const float oy = offp[l * 8 + p * 2 + 1];
            const float a  = e[l * 4 + p] * inv;
            // loc = ref + off/norm;  x_pix = loc_x*W - 0.5
            const float x = fmaf(ox / fw, fw, fmaf(rx, fw, -0.5f));
            const float y = fmaf(oy / fh, fh, fmaf(ry, fh, -0.5f));
            const float x0f = floorf(x), y0f = floorf(y);
            const int   x0  = (int)x0f,  y0  = (int)y0f;
            const float wx1 = x - x0f, wy1 = y - y0f;
            const float wx0 = 1.f - wx1, wy0 = 1.f - wy1;
            const bool vx0 = (unsigned)x0       < (unsigned)Wl[l];
            const bool vx1 = (unsigned)(x0 + 1) < (unsigned)Wl[l];
            const bool vy0 = (unsigned)y0       < (unsigned)Hl[l];
            const bool vy1 = (unsigned)(y0 + 1) < (unsigned)Hl[l];
            float v00 = 0.f, v01 = 0.f, v10 = 0.f, v11 = 0.f;
            if (vy0) {
                const float* r0 = base + (size_t)y0 * Wl[l] * EMBED;
                if (vx0) v00 = r0[(size_t)x0 * EMBED];
                if (vx1) v01 = r0[(size_t)(x0 + 1) * EMBED];
            }
            if (vy1) {
                const float* r1 = base + (size_t)(y0 + 1) * Wl[l] * EMBED;
                if (vx0) v10 = r1[(size_t)x0 * EMBED];
                if (vx1) v11 = r1[(size_t)(x0 + 1) * EMBED];
            }
            const float bil = wy0 * fmaf(wx0, v00, wx1 * v01)
                            + wy1 * fmaf(wx0, v10, wx1 * v11);
            acc = fmaf(a, bil, acc);
        }
    }
    attn[(size_t)bq * EMBED + h * HEADDIM + lane] = acc;
}

// ---------------- launch ----------------
extern "C" void kernel_launch(void* const* d_in, const int* in_sizes, int n_in,
                              void* d_out, int out_size, void* d_ws, size_t ws_size,
                              hipStream_t stream) {
    const float* hs  = (const float*)d_in[0];   // [B,Q,256]
    const float* enc = (const float*)d_in[1];   // [B,S,256]
    const float* rp  = (const float*)d_in[2];   // [B,Q,L,2]
    // d_in[3] = spatial_shapes (static, hardcoded)
    const float* soW = (const float*)d_in[4];   // [192,256]
    const float* soB = (const float*)d_in[5];   // [192]
    const float* awW = (const float*)d_in[6];   // [96,256]
    const float* awB = (const float*)d_in[7];   // [96]
    const float* vW  = (const float*)d_in[8];   // [256,256]
    const float* vB  = (const float*)d_in[9];   // [256]
    const float* oW  = (const float*)d_in[10];  // [256,256]
    const float* oB  = (const float*)d_in[11];  // [256]
    float* out = (float*)d_out;

    const int M = BATCH * QLEN;  // 43008, multiple of 64

    float* value = (float*)d_ws;                 // M*256
    float* offb  = value + (size_t)M * 256;      // M*192
    float* awb   = offb  + (size_t)M * 192;      // M*96
    float* attn  = awb   + (size_t)M * 96;       // M*256

    dim3 blk(256);
    // 1) value projection
    gemm_bias_kernel<<<dim3(4, M / 64), blk, 0, stream>>>(enc, vW, vB, value, M, 256);
    // 2) sampling offsets
    gemm_bias_kernel<<<dim3(3, M / 64), blk, 0, stream>>>(hs, soW, soB, offb, M, 192);
    // 3) attention weights (pre-softmax)
    gemm_bias_kernel<<<dim3(2, M / 64), blk, 0, stream>>>(hs, awW, awB, awb, M, 96);
    // 4) softmax + bilinear sampling + weighted sum -> attn [B*Q, 256]
    msda_sample_kernel<<<dim3(M), blk, 0, stream>>>(value, offb, awb, rp, attn);
    // 5) output projection
    gemm_bias_kernel<<<dim3(4, M / 64), blk, 0, stream>>>(attn, oW, oB, out, M, 256);
}

// Round 2
// 496.496 us; speedup vs baseline: 1.3668x; 1.3668x over previous
//
#include <hip/hip_runtime.h>
#include <hip/hip_bf16.h>

// Problem constants (static per reference)
#define EMBED   256
#define HEADS   8
#define LEVELS  3
#define POINTS  4
#define BATCH   2
#define QLEN    21504
#define SLEN    21504
#define HEADDIM 32

// ---------------- GEMM: C[M,N] = A[M,K=256] @ W[N,K]^T + bias[N] ----------------
#define GEMM_BM 64
#define GEMM_BN 64
#define GEMM_BK 16
#define GEMM_K  256

__global__ __launch_bounds__(256)
void gemm_bias_kernel(const float* __restrict__ A, const float* __restrict__ W,
                      const float* __restrict__ bias, float* __restrict__ C,
                      int M, int N)
{
    __shared__ float As[GEMM_BK][GEMM_BM];
    __shared__ float Ws[GEMM_BK][GEMM_BN];
    const int tid = threadIdx.x;
    const int bm  = blockIdx.y * GEMM_BM;
    const int bn  = blockIdx.x * GEMM_BN;
    const int tm  = (tid >> 4) << 2;   // 0..60 step 4 (row in tile)
    const int tn  = (tid & 15) << 2;   // 0..60 step 4 (col in tile)
    const int lrow = tid >> 2;         // 0..63  (loader row)
    const int lk   = (tid & 3) << 2;   // 0,4,8,12 (loader k base)

    float acc[4][4];
    #pragma unroll
    for (int i = 0; i < 4; ++i)
        #pragma unroll
        for (int j = 0; j < 4; ++j) acc[i][j] = 0.f;

    const float* Aptr = A + (size_t)(bm + lrow) * GEMM_K + lk;
    const bool wvalid = (bn + lrow) < N;
    const float* Wptr = W + (size_t)(wvalid ? (bn + lrow) : 0) * GEMM_K + lk;

    for (int k0 = 0; k0 < GEMM_K; k0 += GEMM_BK) {
        float4 av = *(const float4*)(Aptr + k0);
        float4 wv = make_float4(0.f, 0.f, 0.f, 0.f);
        if (wvalid) wv = *(const float4*)(Wptr + k0);
        __syncthreads();
        As[lk + 0][lrow] = av.x; As[lk + 1][lrow] = av.y;
        As[lk + 2][lrow] = av.z; As[lk + 3][lrow] = av.w;
        Ws[lk + 0][lrow] = wv.x; Ws[lk + 1][lrow] = wv.y;
        Ws[lk + 2][lrow] = wv.z; Ws[lk + 3][lrow] = wv.w;
        __syncthreads();
        #pragma unroll
        for (int kk = 0; kk < GEMM_BK; ++kk) {
            float4 a = *(const float4*)&As[kk][tm];
            float4 b = *(const float4*)&Ws[kk][tn];
            acc[0][0] = fmaf(a.x, b.x, acc[0][0]);
            acc[0][1] = fmaf(a.x, b.y, acc[0][1]);
            acc[0][2] = fmaf(a.x, b.z, acc[0][2]);
            acc[0][3] = fmaf(a.x, b.w, acc[0][3]);
            acc[1][0] = fmaf(a.y, b.x, acc[1][0]);
            acc[1][1] = fmaf(a.y, b.y, acc[1][1]);
            acc[1][2] = fmaf(a.y, b.z, acc[1][2]);
            acc[1][3] = fmaf(a.y, b.w, acc[1][3]);
            acc[2][0] = fmaf(a.z, b.x, acc[2][0]);
            acc[2][1] = fmaf(a.z, b.y, acc[2][1]);
            acc[2][2] = fmaf(a.z, b.z, acc[2][2]);
            acc[2][3] = fmaf(a.z, b.w, acc[2][3]);
            acc[3][0] = fmaf(a.w, b.x, acc[3][0]);
            acc[3][1] = fmaf(a.w, b.y, acc[3][1]);
            acc[3][2] = fmaf(a.w, b.z, acc[3][2]);
            acc[3][3] = fmaf(a.w, b.w, acc[3][3]);
        }
    }

    const int col = bn + tn;
    if (col < N) {
        float4 bv = *(const float4*)(bias + col);
        #pragma unroll
        for (int i = 0; i < 4; ++i) {
            const int row = bm + tm + i;
            float4 o;
            o.x = acc[i][0] + bv.x;
            o.y = acc[i][1] + bv.y;
            o.z = acc[i][2] + bv.z;
            o.w = acc[i][3] + bv.w;
            *(float4*)(C + (size_t)row * N + col) = o;
        }
    }
}

// ---------------- Sampling: LDS-prep + float4 gather ----------------
// Block = 256 threads handles 4 consecutive bq rows x 8 heads = 32 groups.
// Each group has 8 lanes; lane c owns channels [4c, 4c+4) of the head (float4).
// Phase 1: 8 threads/group compute softmax + tap indices + fused bilinear
// weights for the group's 12 points into LDS (once, not once-per-lane).
// Phase 2: every thread does 48 float4 gathers weighted-summed into acc.
// LDS layout: per group 12 points x 8 words {int4 idx, float4 w}; group
// stride = 100 words so the 8 groups within a wave land on distinct banks.
__global__ __launch_bounds__(256)
void msda_sample_kernel(const float* __restrict__ value,  // [B, S, 256]
                        const float* __restrict__ off,    // [B*Q, 192] (h,l,p,2)
                        const float* __restrict__ aw,     // [B*Q, 96]  (h,l,p)
                        const float* __restrict__ ref,    // [B, Q, L, 2]
                        float* __restrict__ attn)         // [B*Q, 256]
{
    __shared__ int prep[32 * 100];   // 12.5 KB

    const int tid = threadIdx.x;
    const int g   = tid >> 3;        // 0..31 : group within block
    const int sub = tid & 7;         // 0..7  : lane within group
    const int lq  = g >> 3;          // 0..3  : local bq
    const int h   = g & 7;           // head
    const int bq  = blockIdx.x * 4 + lq;
    const int b   = bq / QLEN;

    // ---- Phase 1: prep (redundancy x8 for softmax, x1 for per-point work) ----
    {
        const float* awp = aw + (size_t)bq * 96 + h * 12;
        float w[12];
        #pragma unroll
        for (int i = 0; i < 12; ++i) w[i] = awp[i];
        float mx = w[0];
        #pragma unroll
        for (int i = 1; i < 12; ++i) mx = fmaxf(mx, w[i]);
        float s = 0.f;
        #pragma unroll
        for (int i = 0; i < 12; ++i) s += __expf(w[i] - mx);
        const float inv = 1.f / s;

        const float* offp = off + (size_t)bq * 192 + h * 24;
        const float* refp = ref + (size_t)bq * 6;

        const int npts = (sub < 4) ? 2 : 1;
        #pragma unroll
        for (int it = 0; it < 2; ++it) {
            if (it >= npts) break;
            const int p  = sub + it * 8;      // 0..11
            const int l  = p >> 2;
            const int Wl = 128 >> l;          // 128,64,32
            const int Hl = 128 >> l;
            const int st = (l == 0) ? 0 : (l == 1 ? 16384 : 20480);

            const float ox = offp[p * 2 + 0];
            const float oy = offp[p * 2 + 1];
            const float rx = refp[2 * l + 0];
            const float ry = refp[2 * l + 1];
            const float a  = __expf(w[p] - mx) * inv;

            const float x = fmaf(rx, (float)Wl, ox - 0.5f);
            const float y = fmaf(ry, (float)Hl, oy - 0.5f);
            const float x0f = floorf(x), y0f = floorf(y);
            const int   x0  = (int)x0f,  y0  = (int)y0f;
            const float wx1 = x - x0f, wy1 = y - y0f;
            const float wx0 = 1.f - wx1, wy0 = 1.f - wy1;
            const bool vx0 = (unsigned)x0       < (unsigned)Wl;
            const bool vx1 = (unsigned)(x0 + 1) < (unsigned)Wl;
            const bool vy0 = (unsigned)y0       < (unsigned)Hl;
            const bool vy1 = (unsigned)(y0 + 1) < (unsigned)Hl;

            // index in float4 units: (b*SLEN + st + y*Wl + x)*64 + h*8
            const int vbase = b * SLEN + st;
            const int r0 = (vbase + y0 * Wl + x0) * 64 + h * 8;
            int4 idx;
            float4 wv;
            idx.x = (vy0 && vx0) ? r0            : 0;
            idx.y = (vy0 && vx1) ? r0 + 64       : 0;
            idx.z = (vy1 && vx0) ? r0 + Wl * 64  : 0;
            idx.w = (vy1 && vx1) ? r0 + Wl * 64 + 64 : 0;
            wv.x  = (vy0 && vx0) ? wy0 * wx0 * a : 0.f;
            wv.y  = (vy0 && vx1) ? wy0 * wx1 * a : 0.f;
            wv.z  = (vy1 && vx0) ? wy1 * wx0 * a : 0.f;
            wv.w  = (vy1 && vx1) ? wy1 * wx1 * a : 0.f;

            *(int4*)  &prep[g * 100 + p * 8]     = idx;
            *(float4*)&prep[g * 100 + p * 8 + 4] = wv;
        }
    }
    __syncthreads();

    // ---- Phase 2: gather ----
    const float4* vp = (const float4*)value;
    float4 acc = make_float4(0.f, 0.f, 0.f, 0.f);
    #pragma unroll
    for (int p = 0; p < 12; ++p) {
        const int4   idx = *(const int4*)  &prep[g * 100 + p * 8];
        const float4 wv  = *(const float4*)&prep[g * 100 + p * 8 + 4];
        const float4 v0 = vp[idx.x + sub];
        const float4 v1 = vp[idx.y + sub];
        const float4 v2 = vp[idx.z + sub];
        const float4 v3 = vp[idx.w + sub];
        acc.x = fmaf(wv.x, v0.x, acc.x); acc.y = fmaf(wv.x, v0.y, acc.y);
        acc.z = fmaf(wv.x, v0.z, acc.z); acc.w = fmaf(wv.x, v0.w, acc.w);
        acc.x = fmaf(wv.y, v1.x, acc.x); acc.y = fmaf(wv.y, v1.y, acc.y);
        acc.z = fmaf(wv.y, v1.z, acc.z); acc.w = fmaf(wv.y, v1.w, acc.w);
        acc.x = fmaf(wv.z, v2.x, acc.x); acc.y = fmaf(wv.z, v2.y, acc.y);
        acc.z = fmaf(wv.z, v2.z, acc.z); acc.w = fmaf(wv.z, v2.w, acc.w);
        acc.x = fmaf(wv.w, v3.x, acc.x); acc.y = fmaf(wv.w, v3.y, acc.y);
        acc.z = fmaf(wv.w, v3.z, acc.z); acc.w = fmaf(wv.w, v3.w, acc.w);
    }
    ((float4*)attn)[(size_t)bq * 64 + h * 8 + sub] = acc;
}

// ---------------- launch ----------------
extern "C" void kernel_launch(void* const* d_in, const int* in_sizes, int n_in,
                              void* d_out, int out_size, void* d_ws, size_t ws_size,
                              hipStream_t stream) {
    const float* hs  = (const float*)d_in[0];   // [B,Q,256]
    const float* enc = (const float*)d_in[1];   // [B,S,256]
    const float* rp  = (const float*)d_in[2];   // [B,Q,L,2]
    // d_in[3] = spatial_shapes (static, hardcoded)
    const float* soW = (const float*)d_in[4];   // [192,256]
    const float* soB = (const float*)d_in[5];   // [192]
    const float* awW = (const float*)d_in[6];   // [96,256]
    const float* awB = (const float*)d_in[7];   // [96]
    const float* vW  = (const float*)d_in[8];   // [256,256]
    const float* vB  = (const float*)d_in[9];   // [256]
    const float* oW  = (const float*)d_in[10];  // [256,256]
    const float* oB  = (const float*)d_in[11];  // [256]
    float* out = (float*)d_out;

    const int M = BATCH * QLEN;  // 43008, multiple of 64

    float* value = (float*)d_ws;                 // M*256
    float* offb  = value + (size_t)M * 256;      // M*192
    float* awb   = offb  + (size_t)M * 192;      // M*96
    float* attn  = awb   + (size_t)M * 96;       // M*256

    dim3 blk(256);
    // 1) value projection
    gemm_bias_kernel<<<dim3(4, M / 64), blk, 0, stream>>>(enc, vW, vB, value, M, 256);
    // 2) sampling offsets
    gemm_bias_kernel<<<dim3(3, M / 64), blk, 0, stream>>>(hs, soW, soB, offb, M, 192);
    // 3) attention weights (pre-softmax)
    gemm_bias_kernel<<<dim3(2, M / 64), blk, 0, stream>>>(hs, awW, awB, awb, M, 96);
    // 4) softmax + bilinear sampling + weighted sum -> attn [B*Q, 256]
    msda_sample_kernel<<<dim3(M / 4), blk, 0, stream>>>(value, offb, awb, rp, attn);
    // 5) output projection
    gemm_bias_kernel<<<dim3(4, M / 64), blk, 0, stream>>>(attn, oW, oB, out, M, 256);
}

// Round 3
// 279.905 us; speedup vs baseline: 2.4244x; 1.7738x over previous
//
#include <hip/hip_runtime.h>
#include <hip/hip_bf16.h>

#define EMBED   256
#define HEADS   8
#define LEVELS  3
#define POINTS  4
#define BATCH   2
#define QLEN    21504
#define SLEN    21504
#define MTOT    (BATCH * QLEN)   // 43008

typedef __attribute__((ext_vector_type(8))) short short8;
typedef __attribute__((ext_vector_type(4))) float f32x4;

__device__ __forceinline__ short f2bf(float x) {
    unsigned u = __builtin_bit_cast(unsigned, x);
    u += 0x7fffu + ((u >> 16) & 1u);      // RNE (inputs are finite)
    return (short)(u >> 16);
}
__device__ __forceinline__ float bf_lo(unsigned u) {   // low 16 bits -> float
    return __builtin_bit_cast(float, u << 16);
}
__device__ __forceinline__ float bf_hi(unsigned u) {   // high 16 bits -> float
    return __builtin_bit_cast(float, u & 0xffff0000u);
}
__device__ __forceinline__ void async16(const void* g, void* l) {
    __builtin_amdgcn_global_load_lds((const __attribute__((address_space(1))) void*)g,
                                     (__attribute__((address_space(3))) void*)l, 16, 0, 0);
}

// ---------------- fp32 -> bf16 conversion (8 elems/thread) ----------------
__global__ __launch_bounds__(256)
void cvt_bf16_kernel(const float* __restrict__ in, short* __restrict__ out, int n8)
{
    int i = blockIdx.x * 256 + threadIdx.x;
    if (i >= n8) return;
    float4 a = ((const float4*)in)[2 * i];
    float4 b = ((const float4*)in)[2 * i + 1];
    short8 o;
    o[0] = f2bf(a.x); o[1] = f2bf(a.y); o[2] = f2bf(a.z); o[3] = f2bf(a.w);
    o[4] = f2bf(b.x); o[5] = f2bf(b.y); o[6] = f2bf(b.z); o[7] = f2bf(b.w);
    ((short8*)out)[i] = o;
}

// ---------------- weight pack: bf16 weights + concatenated so|aw (padded to 384) ----------------
__global__ __launch_bounds__(256)
void pack_weights_kernel(const float* __restrict__ vW, const float* __restrict__ oW,
                         const float* __restrict__ soW, const float* __restrict__ awW,
                         const float* __restrict__ soB, const float* __restrict__ awB,
                         short* __restrict__ vWb, short* __restrict__ oWb,
                         short* __restrict__ soawWb, float* __restrict__ soawB)
{
    int i = blockIdx.x * 256 + threadIdx.x;
    if (i < 65536) {
        vWb[i] = f2bf(vW[i]);
    } else if (i < 131072) {
        int j = i - 65536;
        oWb[j] = f2bf(oW[j]);
    } else if (i < 229376) {
        int j = i - 131072;            // [384][256]
        int row = j >> 8, k = j & 255;
        float v = (row < 192) ? soW[row * 256 + k]
                 : (row < 288) ? awW[(row - 192) * 256 + k] : 0.f;
        soawWb[j] = f2bf(v);
    } else if (i < 229760) {
        int row = i - 229376;          // [384]
        soawB[row] = (row < 192) ? soB[row] : (row < 288) ? awB[row - 192] : 0.f;
    }
}

// ---------------- bf16 MFMA GEMM: C[M,Npad] = A[M,256] @ W[Npad,256]^T + bias ----------------
// 128x128 tile, 4 waves (2x2 of 64x64), 16x16x32 MFMA, global_load_lds staging,
// XOR-swizzled LDS chunks (chunk=16B): LDS (r, c) holds global chunk c ^ ((r>>1)&3)
// -> fragment ds_read_b128 hits all 32 banks uniformly.
template<bool OUT_BF16>
__global__ __launch_bounds__(256)
void gemm_mfma_kernel(const short* __restrict__ A, const short* __restrict__ Wt,
                      const float* __restrict__ bias, void* __restrict__ Cout, int ldc)
{
    __shared__ short As[128 * 32];
    __shared__ short Bs[128 * 32];
    const int tid  = threadIdx.x;
    const int bm   = blockIdx.y * 128;
    const int bn   = blockIdx.x * 128;
    const int wave = tid >> 6;
    const int lane = tid & 63;
    const int wr   = wave >> 1, wc = wave & 1;
    const int m16  = lane & 15, ko = lane >> 4;
    const int swz  = (m16 >> 1) & 3;

    // staging: 512 chunks of 16B per tile; thread covers chunks tid and tid+256
    const int c0 = tid, c1 = tid + 256;
    const int r0 = c0 >> 2, cg0 = (c0 & 3) ^ ((r0 >> 1) & 3);
    const int r1 = c1 >> 2, cg1 = (c1 & 3) ^ ((r1 >> 1) & 3);
    const short* A0 = A  + (size_t)(bm + r0) * 256 + cg0 * 8;
    const short* A1 = A  + (size_t)(bm + r1) * 256 + cg1 * 8;
    const short* B0 = Wt + (size_t)(bn + r0) * 256 + cg0 * 8;
    const short* B1 = Wt + (size_t)(bn + r1) * 256 + cg1 * 8;
    short* const lA0 = As + c0 * 8;
    short* const lA1 = As + c1 * 8;
    short* const lB0 = Bs + c0 * 8;
    short* const lB1 = Bs + c1 * 8;

    // fragment LDS chunk indices (loop-invariant)
    int aIdx[4], bIdx[4];
    #pragma unroll
    for (int t = 0; t < 4; ++t) {
        aIdx[t] = (wr * 64 + t * 16 + m16) * 4 + (ko ^ swz);
        bIdx[t] = (wc * 64 + t * 16 + m16) * 4 + (ko ^ swz);
    }
    const short8* Asv = (const short8*)As;
    const short8* Bsv = (const short8*)Bs;

    f32x4 acc[4][4];
    #pragma unroll
    for (int i = 0; i < 4; ++i)
        #pragma unroll
        for (int j = 0; j < 4; ++j) acc[i][j] = (f32x4)0.f;

    for (int k0 = 0; k0 < 256; k0 += 32) {
        async16(A0 + k0, lA0);
        async16(A1 + k0, lA1);
        async16(B0 + k0, lB0);
        async16(B1 + k0, lB1);
        __syncthreads();
        short8 af[4], bfr[4];
        #pragma unroll
        for (int t = 0; t < 4; ++t) { af[t] = Asv[aIdx[t]]; bfr[t] = Bsv[bIdx[t]]; }
        #pragma unroll
        for (int i = 0; i < 4; ++i)
            #pragma unroll
            for (int j = 0; j < 4; ++j)
                acc[i][j] = __builtin_amdgcn_mfma_f32_16x16x32_bf16(af[i], bfr[j], acc[i][j], 0, 0, 0);
        __syncthreads();
    }

    // epilogue: C/D layout col=lane&15, row=(lane>>4)*4+reg
    const int rbase = wr * 64 + ko * 4;
    #pragma unroll
    for (int tj = 0; tj < 4; ++tj) {
        const int col = bn + wc * 64 + tj * 16 + m16;
        const float bv = bias[col];
        #pragma unroll
        for (int ti = 0; ti < 4; ++ti) {
            #pragma unroll
            for (int r = 0; r < 4; ++r) {
                const int row = bm + rbase + ti * 16 + r;
                const float v = acc[ti][tj][r] + bv;
                if (OUT_BF16) ((short*)Cout)[(size_t)row * ldc + col] = f2bf(v);
                else          ((float*)Cout)[(size_t)row * ldc + col] = v;
            }
        }
    }
}

// ---------------- Sampling: LDS-prep + bf16x8 gather ----------------
// 64 groups/block, 4 lanes/group; lane owns 8 channels (16B bf16 load per tap).
__global__ __launch_bounds__(256)
void msda_sample_kernel(const short* __restrict__ value,  // [M,256] bf16
                        const float* __restrict__ offaw,  // [M,384]: 0..191 off, 192..287 aw
                        const float* __restrict__ ref,    // [B,Q,L,2] fp32
                        short* __restrict__ attn)         // [M,256] bf16
{
    __shared__ int prep[64 * 100];   // 25.6 KB

    const int tid = threadIdx.x;
    const int g   = tid >> 2;        // 0..63
    const int sub = tid & 3;         // 0..3
    const int lq  = g >> 3;          // 0..7
    const int h   = g & 7;
    const int bq  = blockIdx.x * 8 + lq;
    const int b   = bq / QLEN;

    // ---- Phase 1: per-group prep (4 threads: 3 points each) ----
    {
        const float* awp = offaw + (size_t)bq * 384 + 192 + h * 12;
        float w[12];
        #pragma unroll
        for (int i = 0; i < 12; ++i) w[i] = awp[i];
        float mx = w[0];
        #pragma unroll
        for (int i = 1; i < 12; ++i) mx = fmaxf(mx, w[i]);
        float s = 0.f;
        #pragma unroll
        for (int i = 0; i < 12; ++i) s += __expf(w[i] - mx);
        const float inv = 1.f / s;

        const float* offp = offaw + (size_t)bq * 384 + h * 24;
        const float* refp = ref + (size_t)bq * 6;

        #pragma unroll
        for (int it = 0; it < 3; ++it) {
            const int p  = sub + it * 4;      // 0..11
            const int l  = p >> 2;
            const int Wl = 128 >> l;
            const int st = (l == 0) ? 0 : (l == 1 ? 16384 : 20480);

            const float ox = offp[p * 2 + 0];
            const float oy = offp[p * 2 + 1];
            const float rx = refp[2 * l + 0];
            const float ry = refp[2 * l + 1];
            const float a  = __expf(w[p] - mx) * inv;

            const float x = fmaf(rx, (float)Wl, ox - 0.5f);
            const float y = fmaf(ry, (float)Wl, oy - 0.5f);
            const float x0f = floorf(x), y0f = floorf(y);
            const int   x0  = (int)x0f,  y0  = (int)y0f;
            const float wx1 = x - x0f, wy1 = y - y0f;
            const float wx0 = 1.f - wx1, wy0 = 1.f - wy1;
            const bool vx0 = (unsigned)x0       < (unsigned)Wl;
            const bool vx1 = (unsigned)(x0 + 1) < (unsigned)Wl;
            const bool vy0 = (unsigned)y0       < (unsigned)Wl;
            const bool vy1 = (unsigned)(y0 + 1) < (unsigned)Wl;

            // chunk units (16B = 8 bf16): row chunk = vrow*32 + h*4 (+sub by reader)
            const int r0c = (b * SLEN + st + y0 * Wl + x0) * 32 + h * 4;
            int4 idx; float4 wv;
            idx.x = (vy0 && vx0) ? r0c                : 0;
            idx.y = (vy0 && vx1) ? r0c + 32           : 0;
            idx.z = (vy1 && vx0) ? r0c + Wl * 32      : 0;
            idx.w = (vy1 && vx1) ? r0c + Wl * 32 + 32 : 0;
            wv.x  = (vy0 && vx0) ? wy0 * wx0 * a : 0.f;
            wv.y  = (vy0 && vx1) ? wy0 * wx1 * a : 0.f;
            wv.z  = (vy1 && vx0) ? wy1 * wx0 * a : 0.f;
            wv.w  = (vy1 && vx1) ? wy1 * wx1 * a : 0.f;

            *(int4*)  &prep[g * 100 + p * 8]     = idx;
            *(float4*)&prep[g * 100 + p * 8 + 4] = wv;
        }
    }
    __syncthreads();

    // ---- Phase 2: gather (each tap: 4 lanes x 16B = 64B) ----
    const int4* vp = (const int4*)value;   // one int4 = 8 bf16 channels
    float acc[8];
    #pragma unroll
    for (int j = 0; j < 8; ++j) acc[j] = 0.f;

    #pragma unroll
    for (int p = 0; p < 12; ++p) {
        const int4   idx = *(const int4*)  &prep[g * 100 + p * 8];
        const float4 wv  = *(const float4*)&prep[g * 100 + p * 8 + 4];
        const int4 v0 = vp[idx.x + sub];
        const int4 v1 = vp[idx.y + sub];
        const int4 v2 = vp[idx.z + sub];
        const int4 v3 = vp[idx.w + sub];
        #define ACCUM(V, W) \
            acc[0] = fmaf(W, bf_lo((unsigned)V.x), acc[0]); \
            acc[1] = fmaf(W, bf_hi((unsigned)V.x), acc[1]); \
            acc[2] = fmaf(W, bf_lo((unsigned)V.y), acc[2]); \
            acc[3] = fmaf(W, bf_hi((unsigned)V.y), acc[3]); \
            acc[4] = fmaf(W, bf_lo((unsigned)V.z), acc[4]); \
            acc[5] = fmaf(W, bf_hi((unsigned)V.z), acc[5]); \
            acc[6] = fmaf(W, bf_lo((unsigned)V.w), acc[6]); \
            acc[7] = fmaf(W, bf_hi((unsigned)V.w), acc[7]);
        ACCUM(v0, wv.x) ACCUM(v1, wv.y) ACCUM(v2, wv.z) ACCUM(v3, wv.w)
        #undef ACCUM
    }

    int4 o;
    o.x = ((unsigned)(unsigned short)f2bf(acc[1]) << 16) | (unsigned short)f2bf(acc[0]);
    o.y = ((unsigned)(unsigned short)f2bf(acc[3]) << 16) | (unsigned short)f2bf(acc[2]);
    o.z = ((unsigned)(unsigned short)f2bf(acc[5]) << 16) | (unsigned short)f2bf(acc[4]);
    o.w = ((unsigned)(unsigned short)f2bf(acc[7]) << 16) | (unsigned short)f2bf(acc[6]);
    ((int4*)attn)[(size_t)bq * 32 + h * 4 + sub] = o;
}

// ---------------- launch ----------------
extern "C" void kernel_launch(void* const* d_in, const int* in_sizes, int n_in,
                              void* d_out, int out_size, void* d_ws, size_t ws_size,
                              hipStream_t stream) {
    const float* hs  = (const float*)d_in[0];
    const float* enc = (const float*)d_in[1];
    const float* rp  = (const float*)d_in[2];
    const float* soW = (const float*)d_in[4];
    const float* soB = (const float*)d_in[5];
    const float* awW = (const float*)d_in[6];
    const float* awB = (const float*)d_in[7];
    const float* vW  = (const float*)d_in[8];
    const float* vB  = (const float*)d_in[9];
    const float* oW  = (const float*)d_in[10];
    const float* oB  = (const float*)d_in[11];
    float* out = (float*)d_out;

    const int M = MTOT;                       // 43008
    const size_t ME = (size_t)M * 256;

    short* encb   = (short*)d_ws;             // [M,256] bf16 (later reused as attnb)
    short* hsb    = encb + ME;                // [M,256] bf16
    short* valb   = hsb + ME;                 // [M,256] bf16
    float* offaw  = (float*)(valb + ME);      // [M,384] fp32
    short* vWb    = (short*)(offaw + (size_t)M * 384);
    short* oWb    = vWb + 65536;
    short* soawWb = oWb + 65536;              // [384,256] bf16
    float* soawB  = (float*)(soawWb + 98304); // [384] fp32
    short* attnb  = encb;                     // alias: encb dead after GEMM1

    dim3 blk(256);
    const int n8 = (int)(ME / 8);             // 1376256
    // conversions
    cvt_bf16_kernel<<<dim3((n8 + 255) / 256), blk, 0, stream>>>(enc, encb, n8);
    cvt_bf16_kernel<<<dim3((n8 + 255) / 256), blk, 0, stream>>>(hs, hsb, n8);
    pack_weights_kernel<<<dim3(898), blk, 0, stream>>>(vW, oW, soW, awW, soB, awB,
                                                       vWb, oWb, soawWb, soawB);
    // value projection (bf16 out)
    gemm_mfma_kernel<true><<<dim3(2, M / 128), blk, 0, stream>>>(encb, vWb, vB, valb, 256);
    // fused sampling-offsets + attention-weights (fp32 out, ldc 384)
    gemm_mfma_kernel<false><<<dim3(3, M / 128), blk, 0, stream>>>(hsb, soawWb, soawB, offaw, 384);
    // sampling -> attn bf16
    msda_sample_kernel<<<dim3(M / 8), blk, 0, stream>>>(valb, offaw, rp, attnb);
    // output projection (fp32 out)
    gemm_mfma_kernel<false><<<dim3(2, M / 128), blk, 0, stream>>>(attnb, oWb, oB, out, 256);
}

// Round 4
// 276.522 us; speedup vs baseline: 2.4541x; 1.0122x over previous
//
#include <hip/hip_runtime.h>
#include <hip/hip_bf16.h>

#define EMBED   256
#define HEADS   8
#define LEVELS  3
#define POINTS  4
#define BATCH   2
#define QLEN    21504
#define SLEN    21504
#define MTOT    (BATCH * QLEN)   // 43008

typedef __attribute__((ext_vector_type(8))) short short8;
typedef __attribute__((ext_vector_type(4))) float f32x4;

__device__ __forceinline__ short f2bf(float x) {
    unsigned u = __builtin_bit_cast(unsigned, x);
    u += 0x7fffu + ((u >> 16) & 1u);      // RNE (inputs are finite)
    return (short)(u >> 16);
}
__device__ __forceinline__ float bf_lo(unsigned u) { return __builtin_bit_cast(float, u << 16); }
__device__ __forceinline__ float bf_hi(unsigned u) { return __builtin_bit_cast(float, u & 0xffff0000u); }
__device__ __forceinline__ void async16(const void* g, void* l) {
    __builtin_amdgcn_global_load_lds((const __attribute__((address_space(1))) void*)g,
                                     (__attribute__((address_space(3))) void*)l, 16, 0, 0);
}

// ---------------- fused fp32 -> bf16 conversion for enc and hs ----------------
__global__ __launch_bounds__(256)
void cvt2_bf16_kernel(const float* __restrict__ a, short* __restrict__ ao,
                      const float* __restrict__ b, short* __restrict__ bo, int n8)
{
    int i = blockIdx.x * 256 + threadIdx.x;
    const float* src; short* dst; int j;
    if (i < n8)          { src = a; dst = ao; j = i; }
    else                 { src = b; dst = bo; j = i - n8; }
    float4 x = ((const float4*)src)[2 * j];
    float4 y = ((const float4*)src)[2 * j + 1];
    short8 o;
    o[0] = f2bf(x.x); o[1] = f2bf(x.y); o[2] = f2bf(x.z); o[3] = f2bf(x.w);
    o[4] = f2bf(y.x); o[5] = f2bf(y.y); o[6] = f2bf(y.z); o[7] = f2bf(y.w);
    ((short8*)dst)[j] = o;
}

// ---------------- weight pack ----------------
__global__ __launch_bounds__(256)
void pack_weights_kernel(const float* __restrict__ vW, const float* __restrict__ oW,
                         const float* __restrict__ soW, const float* __restrict__ awW,
                         const float* __restrict__ soB, const float* __restrict__ awB,
                         short* __restrict__ vWb, short* __restrict__ oWb,
                         short* __restrict__ soawWb, float* __restrict__ soawB)
{
    int i = blockIdx.x * 256 + threadIdx.x;
    if (i < 65536) {
        vWb[i] = f2bf(vW[i]);
    } else if (i < 131072) {
        int j = i - 65536;
        oWb[j] = f2bf(oW[j]);
    } else if (i < 229376) {
        int j = i - 131072;            // [384][256]
        int row = j >> 8, k = j & 255;
        float v = (row < 192) ? soW[row * 256 + k]
                 : (row < 288) ? awW[(row - 192) * 256 + k] : 0.f;
        soawWb[j] = f2bf(v);
    } else if (i < 229760) {
        int row = i - 229376;          // [384]
        soawB[row] = (row < 192) ? soB[row] : (row < 288) ? awB[row - 192] : 0.f;
    }
}

// ---------------- shared double-buffered MFMA GEMM body ----------------
// C[128,128] tile = A[128,256] @ W[128,256]^T + bias. 4 waves (2x2 of 64x64),
// 16x16x32 bf16 MFMA. 2-stage LDS pipeline: stage tile k+1 after the barrier,
// compute tile k -> the vmcnt(0) drain at the next barrier covers loads that
// have had a full MFMA block to complete. XOR-swizzled 16B chunks in LDS.
__device__ __forceinline__
void gemm_body(const short* __restrict__ A, const short* __restrict__ Wt,
               const float* __restrict__ bias, void* __restrict__ Cout,
               int ldc, bool out_bf16, int bm, int bn,
               short* __restrict__ As, short* __restrict__ Bs)
{
    const int tid  = threadIdx.x;
    const int wave = tid >> 6;
    const int lane = tid & 63;
    const int wr   = wave >> 1, wc = wave & 1;
    const int m16  = lane & 15, ko = lane >> 4;
    const int swz  = (m16 >> 1) & 3;

    const int c0 = tid, c1 = tid + 256;
    const int r0 = c0 >> 2, cg0 = (c0 & 3) ^ ((r0 >> 1) & 3);
    const int r1 = c1 >> 2, cg1 = (c1 & 3) ^ ((r1 >> 1) & 3);
    const short* A0 = A  + (size_t)(bm + r0) * 256 + cg0 * 8;
    const short* A1 = A  + (size_t)(bm + r1) * 256 + cg1 * 8;
    const short* B0 = Wt + (size_t)(bn + r0) * 256 + cg0 * 8;
    const short* B1 = Wt + (size_t)(bn + r1) * 256 + cg1 * 8;

    int aIdx[4], bIdx[4];
    #pragma unroll
    for (int t = 0; t < 4; ++t) {
        aIdx[t] = (wr * 64 + t * 16 + m16) * 4 + (ko ^ swz);
        bIdx[t] = (wc * 64 + t * 16 + m16) * 4 + (ko ^ swz);
    }

    f32x4 acc[4][4];
    #pragma unroll
    for (int i = 0; i < 4; ++i)
        #pragma unroll
        for (int j = 0; j < 4; ++j) acc[i][j] = (f32x4)0.f;

    // prologue: stage tile 0 into buffer 0
    async16(A0, As + c0 * 8);
    async16(A1, As + c1 * 8);
    async16(B0, Bs + c0 * 8);
    async16(B1, Bs + c1 * 8);

    #pragma unroll
    for (int kt = 0; kt < 8; ++kt) {
        __syncthreads();
        if (kt + 1 < 8) {
            const int nb = (kt + 1) & 1;
            const int kofs = (kt + 1) * 32;
            async16(A0 + kofs, As + nb * 4096 + c0 * 8);
            async16(A1 + kofs, As + nb * 4096 + c1 * 8);
            async16(B0 + kofs, Bs + nb * 4096 + c0 * 8);
            async16(B1 + kofs, Bs + nb * 4096 + c1 * 8);
        }
        const int ofs = (kt & 1) * 512;   // chunk offset into current buffer
        const short8* Asv = (const short8*)As;
        const short8* Bsv = (const short8*)Bs;
        short8 af[4], bfr[4];
        #pragma unroll
        for (int t = 0; t < 4; ++t) { af[t] = Asv[ofs + aIdx[t]]; bfr[t] = Bsv[ofs + bIdx[t]]; }
        #pragma unroll
        for (int i = 0; i < 4; ++i)
            #pragma unroll
            for (int j = 0; j < 4; ++j)
                acc[i][j] = __builtin_amdgcn_mfma_f32_16x16x32_bf16(af[i], bfr[j], acc[i][j], 0, 0, 0);
    }

    // epilogue: C/D layout col=lane&15, row=(lane>>4)*4+reg
    const int rbase = wr * 64 + ko * 4;
    #pragma unroll
    for (int tj = 0; tj < 4; ++tj) {
        const int col = bn + wc * 64 + tj * 16 + m16;
        const float bv = bias[col];
        #pragma unroll
        for (int ti = 0; ti < 4; ++ti) {
            #pragma unroll
            for (int r = 0; r < 4; ++r) {
                const int row = bm + rbase + ti * 16 + r;
                const float v = acc[ti][tj][r] + bv;
                if (out_bf16) ((short*)Cout)[(size_t)row * ldc + col] = f2bf(v);
                else          ((float*)Cout)[(size_t)row * ldc + col] = v;
            }
        }
    }
}

// Merged projection GEMMs: blockIdx.x in [0,2) -> value proj (bf16 out, ldc 256),
// [2,5) -> fused offsets+weights proj (fp32 out, ldc 384). 1680 blocks total.
__global__ __launch_bounds__(256)
void proj_gemm_kernel(const short* __restrict__ encb, const short* __restrict__ vWb,
                      const float* __restrict__ vB, short* __restrict__ valb,
                      const short* __restrict__ hsb, const short* __restrict__ soawWb,
                      const float* __restrict__ soawB, float* __restrict__ offaw)
{
    __shared__ short As[2 * 4096];
    __shared__ short Bs[2 * 4096];
    const int bm = blockIdx.y * 128;
    if (blockIdx.x < 2) {
        gemm_body(encb, vWb, vB, valb, 256, true, bm, blockIdx.x * 128, As, Bs);
    } else {
        gemm_body(hsb, soawWb, soawB, offaw, 384, false, bm, (blockIdx.x - 2) * 128, As, Bs);
    }
}

// Output projection GEMM (fp32 out)
__global__ __launch_bounds__(256)
void out_gemm_kernel(const short* __restrict__ A, const short* __restrict__ Wt,
                     const float* __restrict__ bias, float* __restrict__ C)
{
    __shared__ short As[2 * 4096];
    __shared__ short Bs[2 * 4096];
    gemm_body(A, Wt, bias, C, 256, false, blockIdx.y * 128, blockIdx.x * 128, As, Bs);
}

// ---------------- Sampling: LDS-prep + bf16x8 gather ----------------
__global__ __launch_bounds__(256)
void msda_sample_kernel(const short* __restrict__ value,  // [M,256] bf16
                        const float* __restrict__ offaw,  // [M,384]: 0..191 off, 192..287 aw
                        const float* __restrict__ ref,    // [B,Q,L,2] fp32
                        short* __restrict__ attn)         // [M,256] bf16
{
    __shared__ int prep[64 * 100];   // 25.6 KB

    const int tid = threadIdx.x;
    const int g   = tid >> 2;        // 0..63
    const int sub = tid & 3;         // 0..3
    const int lq  = g >> 3;          // 0..7
    const int h   = g & 7;
    const int bq  = blockIdx.x * 8 + lq;
    const int b   = bq / QLEN;

    // ---- Phase 1: per-group prep (4 threads: 3 points each) ----
    {
        const float* awp = offaw + (size_t)bq * 384 + 192 + h * 12;
        float w[12];
        #pragma unroll
        for (int i = 0; i < 12; ++i) w[i] = awp[i];
        float mx = w[0];
        #pragma unroll
        for (int i = 1; i < 12; ++i) mx = fmaxf(mx, w[i]);
        float s = 0.f;
        #pragma unroll
        for (int i = 0; i < 12; ++i) s += __expf(w[i] - mx);
        const float inv = 1.f / s;

        const float* offp = offaw + (size_t)bq * 384 + h * 24;
        const float* refp = ref + (size_t)bq * 6;

        #pragma unroll
        for (int it = 0; it < 3; ++it) {
            const int p  = sub + it * 4;      // 0..11
            const int l  = p >> 2;
            const int Wl = 128 >> l;
            const int st = (l == 0) ? 0 : (l == 1 ? 16384 : 20480);

            const float ox = offp[p * 2 + 0];
            const float oy = offp[p * 2 + 1];
            const float rx = refp[2 * l + 0];
            const float ry = refp[2 * l + 1];
            const float a  = __expf(w[p] - mx) * inv;

            const float x = fmaf(rx, (float)Wl, ox - 0.5f);
            const float y = fmaf(ry, (float)Wl, oy - 0.5f);
            const float x0f = floorf(x), y0f = floorf(y);
            const int   x0  = (int)x0f,  y0  = (int)y0f;
            const float wx1 = x - x0f, wy1 = y - y0f;
            const float wx0 = 1.f - wx1, wy0 = 1.f - wy1;
            const bool vx0 = (unsigned)x0       < (unsigned)Wl;
            const bool vx1 = (unsigned)(x0 + 1) < (unsigned)Wl;
            const bool vy0 = (unsigned)y0       < (unsigned)Wl;
            const bool vy1 = (unsigned)(y0 + 1) < (unsigned)Wl;

            const int r0c = (b * SLEN + st + y0 * Wl + x0) * 32 + h * 4;
            int4 idx; float4 wv;
            idx.x = (vy0 && vx0) ? r0c                : 0;
            idx.y = (vy0 && vx1) ? r0c + 32           : 0;
            idx.z = (vy1 && vx0) ? r0c + Wl * 32      : 0;
            idx.w = (vy1 && vx1) ? r0c + Wl * 32 + 32 : 0;
            wv.x  = (vy0 && vx0) ? wy0 * wx0 * a : 0.f;
            wv.y  = (vy0 && vx1) ? wy0 * wx1 * a : 0.f;
            wv.z  = (vy1 && vx0) ? wy1 * wx0 * a : 0.f;
            wv.w  = (vy1 && vx1) ? wy1 * wx1 * a : 0.f;

            *(int4*)  &prep[g * 100 + p * 8]     = idx;
            *(float4*)&prep[g * 100 + p * 8 + 4] = wv;
        }
    }
    __syncthreads();

    // ---- Phase 2: gather (each tap: 4 lanes x 16B = 64B) ----
    const int4* vp = (const int4*)value;
    float acc[8];
    #pragma unroll
    for (int j = 0; j < 8; ++j) acc[j] = 0.f;

    #pragma unroll
    for (int p = 0; p < 12; ++p) {
        const int4   idx = *(const int4*)  &prep[g * 100 + p * 8];
        const float4 wv  = *(const float4*)&prep[g * 100 + p * 8 + 4];
        const int4 v0 = vp[idx.x + sub];
        const int4 v1 = vp[idx.y + sub];
        const int4 v2 = vp[idx.z + sub];
        const int4 v3 = vp[idx.w + sub];
        #define ACCUM(V, W) \
            acc[0] = fmaf(W, bf_lo((unsigned)V.x), acc[0]); \
            acc[1] = fmaf(W, bf_hi((unsigned)V.x), acc[1]); \
            acc[2] = fmaf(W, bf_lo((unsigned)V.y), acc[2]); \
            acc[3] = fmaf(W, bf_hi((unsigned)V.y), acc[3]); \
            acc[4] = fmaf(W, bf_lo((unsigned)V.z), acc[4]); \
            acc[5] = fmaf(W, bf_hi((unsigned)V.z), acc[5]); \
            acc[6] = fmaf(W, bf_lo((unsigned)V.w), acc[6]); \
            acc[7] = fmaf(W, bf_hi((unsigned)V.w), acc[7]);
        ACCUM(v0, wv.x) ACCUM(v1, wv.y) ACCUM(v2, wv.z) ACCUM(v3, wv.w)
        #undef ACCUM
    }

    int4 o;
    o.x = ((unsigned)(unsigned short)f2bf(acc[1]) << 16) | (unsigned short)f2bf(acc[0]);
    o.y = ((unsigned)(unsigned short)f2bf(acc[3]) << 16) | (unsigned short)f2bf(acc[2]);
    o.z = ((unsigned)(unsigned short)f2bf(acc[5]) << 16) | (unsigned short)f2bf(acc[4]);
    o.w = ((unsigned)(unsigned short)f2bf(acc[7]) << 16) | (unsigned short)f2bf(acc[6]);
    ((int4*)attn)[(size_t)bq * 32 + h * 4 + sub] = o;
}

// ---------------- launch ----------------
extern "C" void kernel_launch(void* const* d_in, const int* in_sizes, int n_in,
                              void* d_out, int out_size, void* d_ws, size_t ws_size,
                              hipStream_t stream) {
    const float* hs  = (const float*)d_in[0];
    const float* enc = (const float*)d_in[1];
    const float* rp  = (const float*)d_in[2];
    const float* soW = (const float*)d_in[4];
    const float* soB = (const float*)d_in[5];
    const float* awW = (const float*)d_in[6];
    const float* awB = (const float*)d_in[7];
    const float* vW  = (const float*)d_in[8];
    const float* vB  = (const float*)d_in[9];
    const float* oW  = (const float*)d_in[10];
    const float* oB  = (const float*)d_in[11];
    float* out = (float*)d_out;

    const int M = MTOT;                       // 43008
    const size_t ME = (size_t)M * 256;

    short* encb   = (short*)d_ws;             // [M,256] bf16 (reused as attnb)
    short* hsb    = encb + ME;                // [M,256] bf16
    short* valb   = hsb + ME;                 // [M,256] bf16
    float* offaw  = (float*)(valb + ME);      // [M,384] fp32
    short* vWb    = (short*)(offaw + (size_t)M * 384);
    short* oWb    = vWb + 65536;
    short* soawWb = oWb + 65536;              // [384,256] bf16
    float* soawB  = (float*)(soawWb + 98304); // [384] fp32
    short* attnb  = encb;                     // alias: encb dead after proj GEMM

    dim3 blk(256);
    const int n8 = (int)(ME / 8);             // 1376256
    cvt2_bf16_kernel<<<dim3(2 * n8 / 256), blk, 0, stream>>>(enc, encb, hs, hsb, n8);
    pack_weights_kernel<<<dim3(898), blk, 0, stream>>>(vW, oW, soW, awW, soB, awB,
                                                       vWb, oWb, soawWb, soawB);
    // merged value + offsets/weights projections
    proj_gemm_kernel<<<dim3(5, M / 128), blk, 0, stream>>>(encb, vWb, vB, valb,
                                                           hsb, soawWb, soawB, offaw);
    // sampling -> attn bf16
    msda_sample_kernel<<<dim3(M / 8), blk, 0, stream>>>(valb, offaw, rp, attnb);
    // output projection
    out_gemm_kernel<<<dim3(2, M / 128), blk, 0, stream>>>(attnb, oWb, oB, out);
}

// Round 5
// 266.191 us; speedup vs baseline: 2.5494x; 1.0388x over previous
//
#include <hip/hip_runtime.h>
#include <hip/hip_bf16.h>

#define EMBED   256
#define HEADS   8
#define LEVELS  3
#define POINTS  4
#define BATCH   2
#define QLEN    21504
#define SLEN    21504
#define MTOT    (BATCH * QLEN)   // 43008

typedef __attribute__((ext_vector_type(8))) short short8;
typedef __attribute__((ext_vector_type(4))) float f32x4;

__device__ __forceinline__ short f2bf(float x) {
    unsigned u = __builtin_bit_cast(unsigned, x);
    u += 0x7fffu + ((u >> 16) & 1u);      // RNE (inputs are finite)
    return (short)(u >> 16);
}
__device__ __forceinline__ float bf_lo(unsigned u) { return __builtin_bit_cast(float, u << 16); }
__device__ __forceinline__ float bf_hi(unsigned u) { return __builtin_bit_cast(float, u & 0xffff0000u); }
__device__ __forceinline__ void async16(const void* g, void* l) {
    __builtin_amdgcn_global_load_lds((const __attribute__((address_space(1))) void*)g,
                                     (__attribute__((address_space(3))) void*)l, 16, 0, 0);
}

// ---------------- weight pack: bf16 weights + concatenated so|aw (padded to 384) ----------------
__global__ __launch_bounds__(256)
void pack_weights_kernel(const float* __restrict__ vW, const float* __restrict__ oW,
                         const float* __restrict__ soW, const float* __restrict__ awW,
                         const float* __restrict__ soB, const float* __restrict__ awB,
                         short* __restrict__ vWb, short* __restrict__ oWb,
                         short* __restrict__ soawWb, float* __restrict__ soawB)
{
    int i = blockIdx.x * 256 + threadIdx.x;
    if (i < 65536) {
        vWb[i] = f2bf(vW[i]);
    } else if (i < 131072) {
        int j = i - 65536;
        oWb[j] = f2bf(oW[j]);
    } else if (i < 229376) {
        int j = i - 131072;            // [384][256]
        int row = j >> 8, k = j & 255;
        float v = (row < 192) ? soW[row * 256 + k]
                 : (row < 288) ? awW[(row - 192) * 256 + k] : 0.f;
        soawWb[j] = f2bf(v);
    } else if (i < 229760) {
        int row = i - 229376;          // [384]
        soawB[row] = (row < 192) ? soB[row] : (row < 288) ? awB[row - 192] : 0.f;
    }
}

// ---------------- weights-stationary streaming GEMM ----------------
// Block = 256 thr (4 waves) handles 64 rows x 128 cols, K=256, in ONE pass:
//  - whole 128-col group of W (64 KB bf16) preloaded to LDS via global_load_lds
//    (swizzle applied on the GLOBAL side so the LDS dest stays wave-uniform+lane*16)
//  - each wave holds its 16 rows' 8 A-fragments in VGPRs (fp32 A converted in-reg)
//  - single __syncthreads, then 8x8 (ct,kt) MFMA loop with ds_read_b128 B-frags;
//    no barriers, no per-tile staging.
// Swizzle: lds chunk-in-row slot s holds global k-chunk g where
//   g = (s & 24) | ((s ^ col) & 7)   (XOR involution; reader inverts identically)
// -> a wave's 8-lane LDS groups span all 32 banks (conflict-free b128 reads).
template<bool A_FP32, bool OUT_BF16>
__device__ __forceinline__
void stream_gemm(const void* __restrict__ Aptr, const short* __restrict__ Wt,
                 const float* __restrict__ bias, void* __restrict__ Cout,
                 int ldc, int colbase, int rowstrip, short* __restrict__ Ws)
{
    const int tid  = threadIdx.x;
    const int lane = tid & 63;
    const int wv   = tid >> 6;
    const int m16  = lane & 15;
    const int ko   = lane >> 4;

    // ---- preload W[colbase..colbase+128) x 256 -> LDS (4096 x 16B chunks) ----
    #pragma unroll
    for (int i = 0; i < 16; ++i) {
        const int c    = i * 256 + tid;       // lds chunk index (dest = uniform + lane*16)
        const int colL = c >> 5;              // 0..127
        const int cw   = c & 31;              // chunk-in-row slot
        const int csw  = (cw & 24) | ((cw ^ colL) & 7);
        async16(Wt + (((size_t)(colbase + colL)) << 8) + csw * 8, Ws + c * 8);
    }

    // ---- A fragments: row = strip + wave*16 + m16, k = kt*32 + ko*8 .. +8 ----
    const int row = rowstrip + wv * 16 + m16;
    short8 afr[8];
    if (A_FP32) {
        const float* Af = (const float*)Aptr + (size_t)row * 256 + ko * 8;
        #pragma unroll
        for (int kt = 0; kt < 8; ++kt) {
            float4 x = *(const float4*)(Af + kt * 32);
            float4 y = *(const float4*)(Af + kt * 32 + 4);
            short8 t;
            t[0] = f2bf(x.x); t[1] = f2bf(x.y); t[2] = f2bf(x.z); t[3] = f2bf(x.w);
            t[4] = f2bf(y.x); t[5] = f2bf(y.y); t[6] = f2bf(y.z); t[7] = f2bf(y.w);
            afr[kt] = t;
        }
    } else {
        const short* Ab = (const short*)Aptr + (size_t)row * 256 + ko * 8;
        #pragma unroll
        for (int kt = 0; kt < 8; ++kt) afr[kt] = *(const short8*)(Ab + kt * 32);
    }

    __syncthreads();   // drains the global_load_lds preload

    const short8* Wvp = (const short8*)Ws;
    const int r0 = rowstrip + wv * 16 + ko * 4;
    #pragma unroll
    for (int ct = 0; ct < 8; ++ct) {
        const int colL = ct * 16 + m16;
        const int rowc = colL * 32;
        f32x4 a = (f32x4)0.f;
        #pragma unroll
        for (int kt = 0; kt < 8; ++kt) {
            const int g = kt * 4 + ko;
            const int s = (g & 24) | ((g ^ colL) & 7);
            a = __builtin_amdgcn_mfma_f32_16x16x32_bf16(afr[kt], Wvp[rowc + s], a, 0, 0, 0);
        }
        // C/D layout (verified r3/r4): col = lane&15 tile col, row = (lane>>4)*4 + r
        const int col = colbase + colL;
        const float bv = bias[col];
        #pragma unroll
        for (int r = 0; r < 4; ++r) {
            const float v = a[r] + bv;
            if (OUT_BF16) ((short*)Cout)[(size_t)(r0 + r) * ldc + col] = f2bf(v);
            else          ((float*)Cout)[(size_t)(r0 + r) * ldc + col] = v;
        }
    }
}

// Merged projections: blockIdx.x 0-1 -> value proj (enc fp32 -> valb bf16, cols x*128);
// 2-4 -> fused offsets+weights proj (hs fp32 -> offaw fp32, cols (x-2)*128 of 384).
__global__ __launch_bounds__(256)
void proj_gemm_kernel(const float* __restrict__ enc, const short* __restrict__ vWb,
                      const float* __restrict__ vB, short* __restrict__ valb,
                      const float* __restrict__ hs, const short* __restrict__ soawWb,
                      const float* __restrict__ soawB, float* __restrict__ offaw)
{
    __shared__ short Ws[128 * 256];   // 64 KB
    const int rowstrip = blockIdx.y * 64;
    if (blockIdx.x < 2) {
        stream_gemm<true, true>(enc, vWb, vB, valb, 256, blockIdx.x * 128, rowstrip, Ws);
    } else {
        stream_gemm<true, false>(hs, soawWb, soawB, offaw, 384, (blockIdx.x - 2) * 128, rowstrip, Ws);
    }
}

// Output projection: attn bf16 -> out fp32
__global__ __launch_bounds__(256)
void out_gemm_kernel(const short* __restrict__ A, const short* __restrict__ oWb,
                     const float* __restrict__ oB, float* __restrict__ C)
{
    __shared__ short Ws[128 * 256];   // 64 KB
    stream_gemm<false, false>(A, oWb, oB, C, 256, blockIdx.x * 128, blockIdx.y * 64, Ws);
}

// ---------------- Sampling: LDS-prep + bf16x8 gather (unchanged from r3) ----------------
__global__ __launch_bounds__(256)
void msda_sample_kernel(const short* __restrict__ value,  // [M,256] bf16
                        const float* __restrict__ offaw,  // [M,384]: 0..191 off, 192..287 aw
                        const float* __restrict__ ref,    // [B,Q,L,2] fp32
                        short* __restrict__ attn)         // [M,256] bf16
{
    __shared__ int prep[64 * 100];   // 25.6 KB

    const int tid = threadIdx.x;
    const int g   = tid >> 2;        // 0..63
    const int sub = tid & 3;         // 0..3
    const int lq  = g >> 3;          // 0..7
    const int h   = g & 7;
    const int bq  = blockIdx.x * 8 + lq;
    const int b   = bq / QLEN;

    // ---- Phase 1: per-group prep (4 threads: 3 points each) ----
    {
        const float* awp = offaw + (size_t)bq * 384 + 192 + h * 12;
        float w[12];
        #pragma unroll
        for (int i = 0; i < 12; ++i) w[i] = awp[i];
        float mx = w[0];
        #pragma unroll
        for (int i = 1; i < 12; ++i) mx = fmaxf(mx, w[i]);
        float s = 0.f;
        #pragma unroll
        for (int i = 0; i < 12; ++i) s += __expf(w[i] - mx);
        const float inv = 1.f / s;

        const float* offp = offaw + (size_t)bq * 384 + h * 24;
        const float* refp = ref + (size_t)bq * 6;

        #pragma unroll
        for (int it = 0; it < 3; ++it) {
            const int p  = sub + it * 4;      // 0..11
            const int l  = p >> 2;
            const int Wl = 128 >> l;
            const int st = (l == 0) ? 0 : (l == 1 ? 16384 : 20480);

            const float ox = offp[p * 2 + 0];
            const float oy = offp[p * 2 + 1];
            const float rx = refp[2 * l + 0];
            const float ry = refp[2 * l + 1];
            const float a  = __expf(w[p] - mx) * inv;

            const float x = fmaf(rx, (float)Wl, ox - 0.5f);
            const float y = fmaf(ry, (float)Wl, oy - 0.5f);
            const float x0f = floorf(x), y0f = floorf(y);
            const int   x0  = (int)x0f,  y0  = (int)y0f;
            const float wx1 = x - x0f, wy1 = y - y0f;
            const float wx0 = 1.f - wx1, wy0 = 1.f - wy1;
            const bool vx0 = (unsigned)x0       < (unsigned)Wl;
            const bool vx1 = (unsigned)(x0 + 1) < (unsigned)Wl;
            const bool vy0 = (unsigned)y0       < (unsigned)Wl;
            const bool vy1 = (unsigned)(y0 + 1) < (unsigned)Wl;

            const int r0c = (b * SLEN + st + y0 * Wl + x0) * 32 + h * 4;
            int4 idx; float4 wvv;
            idx.x = (vy0 && vx0) ? r0c                : 0;
            idx.y = (vy0 && vx1) ? r0c + 32           : 0;
            idx.z = (vy1 && vx0) ? r0c + Wl * 32      : 0;
            idx.w = (vy1 && vx1) ? r0c + Wl * 32 + 32 : 0;
            wvv.x = (vy0 && vx0) ? wy0 * wx0 * a : 0.f;
            wvv.y = (vy0 && vx1) ? wy0 * wx1 * a : 0.f;
            wvv.z = (vy1 && vx0) ? wy1 * wx0 * a : 0.f;
            wvv.w = (vy1 && vx1) ? wy1 * wx1 * a : 0.f;

            *(int4*)  &prep[g * 100 + p * 8]     = idx;
            *(float4*)&prep[g * 100 + p * 8 + 4] = wvv;
        }
    }
    __syncthreads();

    // ---- Phase 2: gather (each tap: 4 lanes x 16B = 64B) ----
    const int4* vp = (const int4*)value;
    float acc[8];
    #pragma unroll
    for (int j = 0; j < 8; ++j) acc[j] = 0.f;

    #pragma unroll
    for (int p = 0; p < 12; ++p) {
        const int4   idx = *(const int4*)  &prep[g * 100 + p * 8];
        const float4 wvv = *(const float4*)&prep[g * 100 + p * 8 + 4];
        const int4 v0 = vp[idx.x + sub];
        const int4 v1 = vp[idx.y + sub];
        const int4 v2 = vp[idx.z + sub];
        const int4 v3 = vp[idx.w + sub];
        #define ACCUM(V, W) \
            acc[0] = fmaf(W, bf_lo((unsigned)V.x), acc[0]); \
            acc[1] = fmaf(W, bf_hi((unsigned)V.x), acc[1]); \
            acc[2] = fmaf(W, bf_lo((unsigned)V.y), acc[2]); \
            acc[3] = fmaf(W, bf_hi((unsigned)V.y), acc[3]); \
            acc[4] = fmaf(W, bf_lo((unsigned)V.z), acc[4]); \
            acc[5] = fmaf(W, bf_hi((unsigned)V.z), acc[5]); \
            acc[6] = fmaf(W, bf_lo((unsigned)V.w), acc[6]); \
            acc[7] = fmaf(W, bf_hi((unsigned)V.w), acc[7]);
        ACCUM(v0, wvv.x) ACCUM(v1, wvv.y) ACCUM(v2, wvv.z) ACCUM(v3, wvv.w)
        #undef ACCUM
    }

    int4 o;
    o.x = ((unsigned)(unsigned short)f2bf(acc[1]) << 16) | (unsigned short)f2bf(acc[0]);
    o.y = ((unsigned)(unsigned short)f2bf(acc[3]) << 16) | (unsigned short)f2bf(acc[2]);
    o.z = ((unsigned)(unsigned short)f2bf(acc[5]) << 16) | (unsigned short)f2bf(acc[4]);
    o.w = ((unsigned)(unsigned short)f2bf(acc[7]) << 16) | (unsigned short)f2bf(acc[6]);
    ((int4*)attn)[(size_t)bq * 32 + h * 4 + sub] = o;
}

// ---------------- launch ----------------
extern "C" void kernel_launch(void* const* d_in, const int* in_sizes, int n_in,
                              void* d_out, int out_size, void* d_ws, size_t ws_size,
                              hipStream_t stream) {
    const float* hs  = (const float*)d_in[0];
    const float* enc = (const float*)d_in[1];
    const float* rp  = (const float*)d_in[2];
    const float* soW = (const float*)d_in[4];
    const float* soB = (const float*)d_in[5];
    const float* awW = (const float*)d_in[6];
    const float* awB = (const float*)d_in[7];
    const float* vW  = (const float*)d_in[8];
    const float* vB  = (const float*)d_in[9];
    const float* oW  = (const float*)d_in[10];
    const float* oB  = (const float*)d_in[11];
    float* out = (float*)d_out;

    const int M = MTOT;                       // 43008
    const size_t ME = (size_t)M * 256;

    short* valb   = (short*)d_ws;             // [M,256] bf16
    short* attnb  = valb + ME;                // [M,256] bf16
    float* offaw  = (float*)(attnb + ME);     // [M,384] fp32
    short* vWb    = (short*)(offaw + (size_t)M * 384);
    short* oWb    = vWb + 65536;
    short* soawWb = oWb + 65536;              // [384,256] bf16
    float* soawB  = (float*)(soawWb + 98304); // [384] fp32

    dim3 blk(256);
    pack_weights_kernel<<<dim3(898), blk, 0, stream>>>(vW, oW, soW, awW, soB, awB,
                                                       vWb, oWb, soawWb, soawB);
    // merged value + offsets/weights projections (fp32 A converted in-register)
    proj_gemm_kernel<<<dim3(5, M / 64), blk, 0, stream>>>(enc, vWb, vB, valb,
                                                          hs, soawWb, soawB, offaw);
    // sampling -> attn bf16
    msda_sample_kernel<<<dim3(M / 8), blk, 0, stream>>>(valb, offaw, rp, attnb);
    // output projection
    out_gemm_kernel<<<dim3(2, M / 64), blk, 0, stream>>>(attnb, oWb, oB, out);
}

// Round 6
// 244.593 us; speedup vs baseline: 2.7745x; 1.0883x over previous
//
#include <hip/hip_runtime.h>
#include <hip/hip_bf16.h>

#define EMBED   256
#define HEADS   8
#define LEVELS  3
#define POINTS  4
#define BATCH   2
#define QLEN    21504
#define SLEN    21504
#define MTOT    (BATCH * QLEN)   // 43008

typedef __attribute__((ext_vector_type(8))) short short8;
typedef __attribute__((ext_vector_type(4))) float f32x4;

__device__ __forceinline__ short f2bf(float x) {
    unsigned u = __builtin_bit_cast(unsigned, x);
    u += 0x7fffu + ((u >> 16) & 1u);      // RNE (inputs are finite)
    return (short)(u >> 16);
}
__device__ __forceinline__ float bf_lo(unsigned u) { return __builtin_bit_cast(float, u << 16); }
__device__ __forceinline__ float bf_hi(unsigned u) { return __builtin_bit_cast(float, u & 0xffff0000u); }
__device__ __forceinline__ void async16(const void* g, void* l) {
    __builtin_amdgcn_global_load_lds((const __attribute__((address_space(1))) void*)g,
                                     (__attribute__((address_space(3))) void*)l, 16, 0, 0);
}

// ---------------- weight pack: bf16 weights + compact so|aw (288 rows) ----------------
__global__ __launch_bounds__(256)
void pack_weights_kernel(const float* __restrict__ vW, const float* __restrict__ oW,
                         const float* __restrict__ soW, const float* __restrict__ awW,
                         const float* __restrict__ soB, const float* __restrict__ awB,
                         short* __restrict__ vWb, short* __restrict__ oWb,
                         short* __restrict__ soawWb, float* __restrict__ soawB)
{
    int i = blockIdx.x * 256 + threadIdx.x;
    if (i < 65536) {
        vWb[i] = f2bf(vW[i]);
    } else if (i < 131072) {
        int j = i - 65536;
        oWb[j] = f2bf(oW[j]);
    } else if (i < 204800) {
        int j = i - 131072;            // [288][256]
        int row = j >> 8, k = j & 255;
        float v = (row < 192) ? soW[row * 256 + k] : awW[(row - 192) * 256 + k];
        soawWb[j] = f2bf(v);
    } else if (i < 205088) {
        int row = i - 204800;          // [288]
        soawB[row] = (row < 192) ? soB[row] : awB[row - 192];
    }
}

// ---------------- A-stationary GEMM: A read ONCE, W col-groups cycled via LDS ----
// Block = 512 thr (8 waves) holds 128 rows of A as bf16 MFMA fragments in VGPRs
// (wave w -> rows strip + w*16 + m16; 8 k-frags of 8 bf16). For each column
// group (<=128 cols, <=64 KB W in LDS): stage via global_load_lds with a
// global-side XOR swizzle, barrier, MFMA sweep, store, barrier, next group.
// Fragment/epilogue mappings identical to the r3-r5 verified kernels.
__device__ __forceinline__
void astat_gemm(const short8* __restrict__ afr, const short* __restrict__ Wt,
                const float* __restrict__ bias, int ngroups, int gcols,
                int rowstrip, short* __restrict__ Ws,
                // epilogue: mode 0 = fp32 [row*ldc+col]; 1 = bf16 head-major value
                int mode, int ldc, void* __restrict__ Cout)
{
    const int tid  = threadIdx.x;
    const int lane = tid & 63;
    const int wv   = tid >> 6;
    const int m16  = lane & 15;
    const int ko   = lane >> 4;
    const int nch  = gcols * 32;          // 16B chunks per group
    const int r0   = rowstrip + wv * 16 + ko * 4;

    for (int gidx = 0; gidx < ngroups; ++gidx) {
        const int colbase = gidx * gcols;
        for (int c = tid; c < nch; c += 512) {
            const int colL = c >> 5;
            const int cw   = c & 31;
            const int csw  = (cw & 24) | ((cw ^ colL) & 7);
            async16(Wt + (((size_t)(colbase + colL)) << 8) + csw * 8, Ws + c * 8);
        }
        __syncthreads();
        const short8* Wvp = (const short8*)Ws;
        const int nct = gcols >> 4;
        for (int ct = 0; ct < nct; ++ct) {
            const int colL = ct * 16 + m16;
            f32x4 a = (f32x4)0.f;
            #pragma unroll
            for (int kt = 0; kt < 8; ++kt) {
                const int g = kt * 4 + ko;
                const int s = (g & 24) | ((g ^ colL) & 7);
                a = __builtin_amdgcn_mfma_f32_16x16x32_bf16(afr[kt], Wvp[colL * 32 + s], a, 0, 0, 0);
            }
            const int col = colbase + colL;
            const float bv = bias[col];
            if (mode == 1) {
                // value: bf16 head-major [B,H,S,32]
                const int h = col >> 5, ch = col & 31;
                #pragma unroll
                for (int r = 0; r < 4; ++r) {
                    const int rg = r0 + r;
                    const int b  = (rg >= SLEN) ? 1 : 0;
                    const int sx = rg - b * SLEN;
                    ((short*)Cout)[(((size_t)(b * 8 + h)) * SLEN + sx) * 32 + ch] = f2bf(a[r] + bv);
                }
            } else {
                #pragma unroll
                for (int r = 0; r < 4; ++r)
                    ((float*)Cout)[(size_t)(r0 + r) * ldc + col] = a[r] + bv;
            }
        }
        __syncthreads();
    }
}

// Projections: blockIdx.x==0 -> value proj (A=enc), ==1 -> offsets+weights (A=hs).
__global__ __launch_bounds__(512)
void proj_gemm_kernel(const float* __restrict__ enc, const short* __restrict__ vWb,
                      const float* __restrict__ vB, short* __restrict__ valb,
                      const float* __restrict__ hs, const short* __restrict__ soawWb,
                      const float* __restrict__ soawB, float* __restrict__ offaw)
{
    __shared__ short Ws[128 * 256];   // 64 KB
    const int tid = threadIdx.x;
    const int lane = tid & 63, wv = tid >> 6;
    const int m16 = lane & 15, ko = lane >> 4;
    const int rowstrip = blockIdx.y * 128;
    const bool isVal = (blockIdx.x == 0);
    const float* A = isVal ? enc : hs;
    const int row = rowstrip + wv * 16 + m16;

    short8 afr[8];
    const float* Af = A + (size_t)row * 256 + ko * 8;
    #pragma unroll
    for (int kt = 0; kt < 8; ++kt) {
        float4 x = *(const float4*)(Af + kt * 32);
        float4 y = *(const float4*)(Af + kt * 32 + 4);
        short8 t;
        t[0] = f2bf(x.x); t[1] = f2bf(x.y); t[2] = f2bf(x.z); t[3] = f2bf(x.w);
        t[4] = f2bf(y.x); t[5] = f2bf(y.y); t[6] = f2bf(y.z); t[7] = f2bf(y.w);
        afr[kt] = t;
    }

    if (isVal) astat_gemm(afr, vWb,    vB,    2, 128, rowstrip, Ws, 1, 256, valb);
    else       astat_gemm(afr, soawWb, soawB, 3,  96, rowstrip, Ws, 0, 288, offaw);
}

// Output projection: A = attn bf16 [M,256], read once; out fp32.
__global__ __launch_bounds__(512)
void out_gemm_kernel(const short* __restrict__ A, const short* __restrict__ oWb,
                     const float* __restrict__ oB, float* __restrict__ C)
{
    __shared__ short Ws[128 * 256];   // 64 KB
    const int tid = threadIdx.x;
    const int lane = tid & 63, wv = tid >> 6;
    const int m16 = lane & 15, ko = lane >> 4;
    const int rowstrip = blockIdx.x * 128;
    const int row = rowstrip + wv * 16 + m16;

    short8 afr[8];
    const short* Ab = A + (size_t)row * 256 + ko * 8;
    #pragma unroll
    for (int kt = 0; kt < 8; ++kt) afr[kt] = *(const short8*)(Ab + kt * 32);

    astat_gemm(afr, oWb, oB, 2, 128, rowstrip, Ws, 0, 256, C);
}

// ---------------- Sampling: head-major value, 8-lane groups, 128B pair-loads ----
// value [B,H,S,32] bf16: one texel's head-slice = 64 B; x-adjacent pair = 128 B
// contiguous. Group = 8 lanes (texel t = sub>>2, channel chunk = sub&3); per
// point only 2 loads (row y0 pair, row y1 pair), each 8x16B = 128 B contiguous.
// Prep (per group, once): softmax + clamped pair-base indices + 4 fused weights.
__global__ __launch_bounds__(256)
void msda_sample_kernel(const short* __restrict__ value,  // [B,H,S,32] bf16
                        const float* __restrict__ offaw,  // [M,288]: 0..191 off, 192..287 aw
                        const float* __restrict__ ref,    // [B,Q,L,2] fp32
                        short* __restrict__ attn)         // [M,256] bf16
{
    __shared__ int prep[32 * 76];    // per group: 12 pts x 6 words {i0,i1,w00,w01,w10,w11}

    const int tid = threadIdx.x;
    const int g   = tid >> 3;        // 0..31
    const int sub = tid & 7;         // 0..7
    const int t   = sub >> 2;        // texel within pair
    const int lq  = g >> 3;          // 0..3
    const int h   = g & 7;
    const int bq  = blockIdx.x * 4 + lq;
    const int b   = (bq >= QLEN) ? 1 : 0;

    // ---- Phase 1: prep. sub 0..7 -> point sub; sub 0..3 also point sub+8 ----
    {
        const float* awp = offaw + (size_t)bq * 288 + 192 + h * 12;
        float w[12];
        #pragma unroll
        for (int i = 0; i < 12; ++i) w[i] = awp[i];
        float mx = w[0];
        #pragma unroll
        for (int i = 1; i < 12; ++i) mx = fmaxf(mx, w[i]);
        float s = 0.f;
        #pragma unroll
        for (int i = 0; i < 12; ++i) s += __expf(w[i] - mx);
        const float inv = 1.f / s;

        const float* offp = offaw + (size_t)bq * 288 + h * 24;
        const float* refp = ref + (size_t)bq * 6;
        const int npts = (sub < 4) ? 2 : 1;
        #pragma unroll
        for (int it = 0; it < 2; ++it) {
            if (it >= npts) break;
            const int p  = sub + it * 8;      // 0..11
            const int l  = p >> 2;
            const int Wl = 128 >> l;
            const int st = (l == 0) ? 0 : (l == 1 ? 16384 : 20480);

            const float ox = offp[p * 2 + 0];
            const float oy = offp[p * 2 + 1];
            const float rx = refp[2 * l + 0];
            const float ry = refp[2 * l + 1];
            const float a  = __expf(w[p] - mx) * inv;

            const float x = fmaf(rx, (float)Wl, ox - 0.5f);
            const float y = fmaf(ry, (float)Wl, oy - 0.5f);
            const float x0f = floorf(x), y0f = floorf(y);
            const int   x0  = (int)x0f,  y0  = (int)y0f;
            const float wx1 = x - x0f, wy1 = y - y0f;
            const float wx0 = 1.f - wx1, wy0 = 1.f - wy1;
            const bool vy0 = (unsigned)y0       < (unsigned)Wl;
            const bool vy1 = (unsigned)(y0 + 1) < (unsigned)Wl;

            const int xs = min(max(x0, 0), Wl - 2);   // pair start, always in-bounds
            // per-texel x-weights (0 when that texel isn't a valid bilinear corner)
            const float wl0 = (xs == x0) ? wx0 : ((xs == x0 + 1) ? wx1 : 0.f);
            const float wl1 = (xs == x0) ? wx1 : ((xs + 1 == x0) ? wx0 : 0.f);

            const int hb = (b * 8 + h) * SLEN + st;
            const int i0 = vy0 ? (hb + y0 * Wl + xs) * 4       : 0;
            const int i1 = vy1 ? (hb + (y0 + 1) * Wl + xs) * 4 : 0;

            int* pp = &prep[g * 76 + p * 6];
            pp[0] = i0;
            pp[1] = i1;
            pp[2] = __builtin_bit_cast(int, vy0 ? wy0 * wl0 * a : 0.f);
            pp[3] = __builtin_bit_cast(int, vy0 ? wy0 * wl1 * a : 0.f);
            pp[4] = __builtin_bit_cast(int, vy1 ? wy1 * wl0 * a : 0.f);
            pp[5] = __builtin_bit_cast(int, vy1 ? wy1 * wl1 * a : 0.f);
        }
    }
    __syncthreads();

    // ---- Phase 2: gather ----
    const int4* vp = (const int4*)value;
    float acc[8];
    #pragma unroll
    for (int j = 0; j < 8; ++j) acc[j] = 0.f;

    #pragma unroll
    for (int p = 0; p < 12; ++p) {
        const int* pp = &prep[g * 76 + p * 6];
        const int i0 = pp[0];
        const int i1 = pp[1];
        const float w0 = __builtin_bit_cast(float, pp[2 + t]);
        const float w1 = __builtin_bit_cast(float, pp[4 + t]);
        const int4 v0 = vp[i0 + sub];
        const int4 v1 = vp[i1 + sub];
        #define ACCUM(V, W) \
            acc[0] = fmaf(W, bf_lo((unsigned)V.x), acc[0]); \
            acc[1] = fmaf(W, bf_hi((unsigned)V.x), acc[1]); \
            acc[2] = fmaf(W, bf_lo((unsigned)V.y), acc[2]); \
            acc[3] = fmaf(W, bf_hi((unsigned)V.y), acc[3]); \
            acc[4] = fmaf(W, bf_lo((unsigned)V.z), acc[4]); \
            acc[5] = fmaf(W, bf_hi((unsigned)V.z), acc[5]); \
            acc[6] = fmaf(W, bf_lo((unsigned)V.w), acc[6]); \
            acc[7] = fmaf(W, bf_hi((unsigned)V.w), acc[7]);
        ACCUM(v0, w0) ACCUM(v1, w1)
        #undef ACCUM
    }

    // combine the two texel partial sums (lane <-> lane^4, same 8-lane group)
    #pragma unroll
    for (int j = 0; j < 8; ++j) acc[j] += __shfl_xor(acc[j], 4);

    if (sub < 4) {
        int4 o;
        o.x = ((unsigned)(unsigned short)f2bf(acc[1]) << 16) | (unsigned short)f2bf(acc[0]);
        o.y = ((unsigned)(unsigned short)f2bf(acc[3]) << 16) | (unsigned short)f2bf(acc[2]);
        o.z = ((unsigned)(unsigned short)f2bf(acc[5]) << 16) | (unsigned short)f2bf(acc[4]);
        o.w = ((unsigned)(unsigned short)f2bf(acc[7]) << 16) | (unsigned short)f2bf(acc[6]);
        ((int4*)attn)[(size_t)bq * 32 + h * 4 + sub] = o;
    }
}

// ---------------- launch ----------------
extern "C" void kernel_launch(void* const* d_in, const int* in_sizes, int n_in,
                              void* d_out, int out_size, void* d_ws, size_t ws_size,
                              hipStream_t stream) {
    const float* hs  = (const float*)d_in[0];
    const float* enc = (const float*)d_in[1];
    const float* rp  = (const float*)d_in[2];
    const float* soW = (const float*)d_in[4];
    const float* soB = (const float*)d_in[5];
    const float* awW = (const float*)d_in[6];
    const float* awB = (const float*)d_in[7];
    const float* vW  = (const float*)d_in[8];
    const float* vB  = (const float*)d_in[9];
    const float* oW  = (const float*)d_in[10];
    const float* oB  = (const float*)d_in[11];
    float* out = (float*)d_out;

    const int M = MTOT;                       // 43008
    const size_t ME = (size_t)M * 256;

    short* valb   = (short*)d_ws;             // [B,H,S,32] bf16 head-major
    short* attnb  = valb + ME;                // [M,256] bf16
    float* offaw  = (float*)(attnb + ME);     // [M,288] fp32 compact
    short* vWb    = (short*)(offaw + (size_t)M * 288);
    short* oWb    = vWb + 65536;
    short* soawWb = oWb + 65536;              // [288,256] bf16
    float* soawB  = (float*)(soawWb + 73728); // [288] fp32

    pack_weights_kernel<<<dim3(802), dim3(256), 0, stream>>>(vW, oW, soW, awW, soB, awB,
                                                             vWb, oWb, soawWb, soawB);
    // value + offsets/weights projections (A read once per kernel part)
    proj_gemm_kernel<<<dim3(2, M / 128), dim3(512), 0, stream>>>(enc, vWb, vB, valb,
                                                                 hs, soawWb, soawB, offaw);
    // sampling -> attn bf16
    msda_sample_kernel<<<dim3(M / 4), dim3(256), 0, stream>>>(valb, offaw, rp, attnb);
    // output projection
    out_gemm_kernel<<<dim3(M / 128), dim3(512), 0, stream>>>(attnb, oWb, oB, out);
}